// Round 5
// baseline (180.673 us; speedup 1.0000x reference)
//
#include <hip/hip_runtime.h>

#define DEV __device__ __forceinline__

typedef unsigned short u16;
typedef __attribute__((ext_vector_type(8))) short bf16x8;   // 8 bf16 (4 VGPRs)
typedef __attribute__((ext_vector_type(8))) unsigned short u16x8;
typedef __attribute__((ext_vector_type(4))) float f32x4;

constexpr int Bz = 32, Lz = 1024, Dz = 384, Fz = 384, KWz = 3, Mz = 4096;
constexpr float EPS = 1e-5f;

DEV u16 f2bf(float f) {  // RNE f32 -> bf16
  unsigned u = __float_as_uint(f);
  u += 0x7fffu + ((u >> 16) & 1u);
  return (u16)(u >> 16);
}

typedef __attribute__((address_space(1))) const unsigned char ga_t;
typedef __attribute__((address_space(3))) unsigned char la_t;
DEV void gload16(const void* g, void* l) {
  // async global->LDS, 16B per lane; LDS dest is wave-uniform base + lane*16
  __builtin_amdgcn_global_load_lds((ga_t*)g, (la_t*)l, 16, 0, 0);
}

// -- fused: convert x -> padded bf16, weight prep, halo zero, cumsum+search --
__global__ __launch_bounds__(1024) void k_pre(
    const float* __restrict__ x, u16* __restrict__ xbf,
    const float* __restrict__ w1, const float* __restrict__ w2,
    u16* __restrict__ w1t, u16* __restrict__ w2t, u16* __restrict__ h1,
    const int* __restrict__ tgt, int* __restrict__ idxb) {
  __shared__ int sc[Lz];
  constexpr int CONV_BLKS = (Bz * Lz * Dz / 8) / 1024;   // 1536
  constexpr int WT = KWz * Fz * Dz;                      // 442368
  constexpr int PREP_ELEMS = 2 * WT + 2 * Bz * 2 * Dz;   // 933888
  constexpr int PREP_BLKS = (PREP_ELEMS + 1023) / 1024;  // 912
  const int tid = threadIdx.x;

  if (blockIdx.x < CONV_BLKS) {  // ---- x f32 -> bf16, padded rows ----
    int gid = blockIdx.x * 1024 + tid;
    size_t e = (size_t)gid * 8;
    float4 v0 = *reinterpret_cast<const float4*>(x + e);
    float4 v1 = *reinterpret_cast<const float4*>(x + e + 4);
    int d = (int)(e % Dz);               // 8 | 384 -> never crosses a row
    int l = (int)((e / Dz) % Lz);
    int b = (int)(e / ((size_t)Dz * Lz));
    u16x8 u;
    u[0] = f2bf(v0.x); u[1] = f2bf(v0.y); u[2] = f2bf(v0.z); u[3] = f2bf(v0.w);
    u[4] = f2bf(v1.x); u[5] = f2bf(v1.y); u[6] = f2bf(v1.z); u[7] = f2bf(v1.w);
    *reinterpret_cast<u16x8*>(xbf + ((size_t)(b * (Lz + 2) + l + 1)) * Dz + d) = u;
    return;
  }
  if (blockIdx.x < CONV_BLKS + PREP_BLKS) {  // ---- weights + halos ----
    int gid = (blockIdx.x - CONV_BLKS) * 1024 + tid;
    if (gid < WT) {
      int k = gid / (Fz * Dz), rem = gid % (Fz * Dz);
      int f = rem / Dz, d = rem % Dz;
      w1t[gid] = f2bf(w1[(f * Dz + d) * KWz + k]);
    } else if (gid < 2 * WT) {
      int g2 = gid - WT;
      int k = g2 / (Fz * Fz), rem = g2 % (Fz * Fz);
      int co = rem / Fz, ci = rem % Fz;
      w2t[g2] = f2bf(w2[(co * Fz + ci) * KWz + k]);
    } else if (gid < PREP_ELEMS) {
      int p = gid - 2 * WT;
      u16* buf = (p < Bz * 2 * Dz) ? xbf : h1;
      int q = p % (Bz * 2 * Dz);
      int b = q / (2 * Dz), r = (q / Dz) & 1, d = q % Dz;
      size_t row = (size_t)b * (Lz + 2) + (r ? (Lz + 1) : 0);
      buf[row * Dz + d] = 0;
    }
    return;
  }
  // ---- cumsum + searchsorted(right) ----
  int b = blockIdx.x - CONV_BLKS - PREP_BLKS;
  sc[tid] = tgt[b * Lz + tid];
  __syncthreads();
  for (int off = 1; off < Lz; off <<= 1) {
    int add = (tid >= off) ? sc[tid - off] : 0;
    __syncthreads();
    sc[tid] += add;
    __syncthreads();
  }
  int total = sc[Lz - 1];
  for (int t = tid; t < Mz; t += 1024) {
    int lo = 0, hi = Lz;
    while (lo < hi) {
      int mid = (lo + hi) >> 1;
      if (sc[mid] > t) hi = mid; else lo = mid + 1;
    }
    int iv = (t < total) ? (lo > Lz - 1 ? Lz - 1 : lo) : -1;
    idxb[b * Mz + t] = iv;
  }
}

// --------- fused conv1d(K=3,'same') + LayerNorm + ReLU (+ final dot) --------
// Waves 0-7: GEMM [128 rows]x[384 cols], K = 36 steps of 32, wave tile 64x96,
//   triple-buffered LDS, counted vmcnt(4) + raw s_barrier (T3+T4).
// Waves 8-11: gather 256 output rows/block, 2 rows/interval, depth-2 prefetch,
//   matching the block barrier cadence exactly.
// Barrier count per path: 36 (loop) + 2 (epilogue) + (LAYER==2 ? 1 : 0).
template <int LAYER>
__global__ __launch_bounds__(768, 3) void k_conv(
    const u16* __restrict__ in,    // [Bz][Lz+2][384] bf16 (halo-padded)
    const u16* __restrict__ wt,    // [3][384 out][384 in] bf16
    const float* __restrict__ cbias,
    const float* __restrict__ lng, const float* __restrict__ lnb,
    u16* __restrict__ hout,        // LAYER==1: padded output buffer
    const float* __restrict__ lw, const float* __restrict__ lbias,
    float* __restrict__ dur,       // LAYER==2: [B*L]
    const float* __restrict__ xf,  // gather: source rows (f32)
    const int* __restrict__ idxb,  // gather: per-frame phoneme idx (-1 = pad)
    float* __restrict__ out0)      // gather: [B*M*D]
{
  __shared__ __align__(16) u16 Ash[3][128 * 32];   // 3 x 8KB
  __shared__ __align__(16) u16 Bsh[3][384 * 32];   // 3 x 24KB
  __shared__ float s_sum[4][128], s_sq[4][128], s_dot[4][128];

  const int tid = threadIdx.x;
  const int lane = tid & 63, wave = tid >> 6;   // 12 waves: 8 conv + 4 gather
  const int l15 = lane & 15, lh = lane >> 4;
  const int b = blockIdx.x >> 3, l0 = (blockIdx.x & 7) << 7;

  if (wave >= 8) {  // ================= gather waves =================
    const int gw = wave - 8;
    const int rbase = (LAYER == 1 ? 0 : (Bz * Mz) / 2) + blockIdx.x * 256 + gw * 64;
    float4 ca0, cb0, ca1, cb1, na0, nb0, na1, nb1;
    auto ldrow = [&](int row, float4& a, float4& bq) {
      int iv = idxb[row];
      if (iv < 0) {
        a = make_float4(0.f, 0.f, 0.f, 0.f);
        bq = a;
      } else {
        const float4* src =
            reinterpret_cast<const float4*>(xf + ((size_t)(row >> 12) * Lz + iv) * Dz);
        a = src[lane];
        bq = (lane < 32) ? src[64 + lane] : a;
      }
    };
    auto strow = [&](int row, float4 a, float4 bq) {
      float4* dst = reinterpret_cast<float4*>(out0 + (size_t)row * Dz);
      dst[lane] = a;
      if (lane < 32) dst[64 + lane] = bq;
    };
    ldrow(rbase + 0, ca0, cb0);
    ldrow(rbase + 1, ca1, cb1);
    for (int kt = 0; kt < 36; ++kt) {
      if (kt < 31) {
        ldrow(rbase + 2 * (kt + 1), na0, nb0);
        ldrow(rbase + 2 * (kt + 1) + 1, na1, nb1);
      }
      if (kt < 32) {
        strow(rbase + 2 * kt, ca0, cb0);
        strow(rbase + 2 * kt + 1, ca1, cb1);
      }
      ca0 = na0; cb0 = nb0; ca1 = na1; cb1 = nb1;
      __builtin_amdgcn_s_barrier();              // 1..36
    }
    __builtin_amdgcn_s_barrier();                // 37
    __builtin_amdgcn_s_barrier();                // 38
    if constexpr (LAYER == 2) __builtin_amdgcn_s_barrier();  // 39
    return;
  }

  // ================= conv waves (identical to R4 schedule) =================
  const int wr = wave >> 2, wc = wave & 3;      // 2 x 4 wave grid

  const u16* in_row = in + ((size_t)(b * (Lz + 2) + l0)) * 384;
  int gof[4], ldo[4];
  bool isa[4];
  #pragma unroll
  for (int i = 0; i < 4; ++i) {
    int c = wave + 8 * i;
    bool a = (c < 8);
    int cb = a ? c : c - 8;
    int slot = cb * 64 + lane, r = slot >> 2, q = slot & 3;
    int ks = q ^ ((r >> 1) & 3);             // XOR slot swizzle (involution)
    gof[i] = r * 384 + ks * 8;
    ldo[i] = cb * 512;
    isa[i] = a;
  }

  auto STAGE = [&](int kt, int buf) {
    int tap = kt / 12;
    int d0 = (kt - tap * 12) * 32;
    const u16* sa = in_row + tap * 384 + d0;
    const u16* sb = wt + tap * (384 * 384) + d0;
    #pragma unroll
    for (int i = 0; i < 4; ++i) {
      if (isa[i]) gload16(sa + gof[i], &Ash[buf][ldo[i]]);
      else        gload16(sb + gof[i], &Bsh[buf][ldo[i]]);
    }
  };

  int aoff[4], boff[6];
  #pragma unroll
  for (int m = 0; m < 4; ++m) {
    int r = wr * 64 + m * 16 + l15;
    aoff[m] = r * 32 + (lh ^ ((r >> 1) & 3)) * 8;
  }
  #pragma unroll
  for (int n = 0; n < 6; ++n) {
    int c = wc * 96 + n * 16 + l15;
    boff[n] = c * 32 + (lh ^ ((c >> 1) & 3)) * 8;
  }

  f32x4 acc[4][6] = {};

  STAGE(0, 0);
  STAGE(1, 1);
  int cur = 0;
  for (int kt = 0; kt < 36; ++kt) {
    if (kt < 35) asm volatile("s_waitcnt vmcnt(4)" ::: "memory");
    else         asm volatile("s_waitcnt vmcnt(0)" ::: "memory");
    __builtin_amdgcn_s_barrier();              // 1..36
    __builtin_amdgcn_sched_barrier(0);
    bf16x8 av[4], bv[6];
    #pragma unroll
    for (int m = 0; m < 4; ++m)
      av[m] = *reinterpret_cast<const bf16x8*>(&Ash[cur][aoff[m]]);
    #pragma unroll
    for (int n = 0; n < 6; ++n)
      bv[n] = *reinterpret_cast<const bf16x8*>(&Bsh[cur][boff[n]]);
    if (kt < 34) {
      int nb = cur + 2; if (nb >= 3) nb -= 3;
      STAGE(kt + 2, nb);  // buf last read at step kt-1; barrier-protected
    }
    #pragma unroll
    for (int m = 0; m < 4; ++m)
      #pragma unroll
      for (int n = 0; n < 6; ++n)
        acc[m][n] =
            __builtin_amdgcn_mfma_f32_16x16x32_bf16(av[m], bv[n], acc[m][n], 0, 0, 0);
    cur = (cur == 2) ? 0 : cur + 1;
  }

  // ---- epilogue: bias + LayerNorm(F) + ReLU, then store bf16 or dot(lw) ----
  __syncthreads();                             // 37
  float gv[6], bvv[6], cbv[6], lwv[6];
  #pragma unroll
  for (int n = 0; n < 6; ++n) {
    int c = wc * 96 + n * 16 + l15;
    gv[n] = lng[c]; bvv[n] = lnb[c]; cbv[n] = cbias[c];
    lwv[n] = (LAYER == 2) ? lw[c] : 0.f;
  }
  #pragma unroll
  for (int m = 0; m < 4; ++m) {
    #pragma unroll
    for (int r = 0; r < 4; ++r) {
      float s = 0.f, q2 = 0.f;
      #pragma unroll
      for (int n = 0; n < 6; ++n) {
        float v = acc[m][n][r] + cbv[n];
        s += v; q2 += v * v;
      }
      #pragma unroll
      for (int off = 1; off < 16; off <<= 1) {
        s += __shfl_xor(s, off);
        q2 += __shfl_xor(q2, off);
      }
      if (l15 == 0) {
        int row = wr * 64 + m * 16 + lh * 4 + r;
        s_sum[wc][row] = s;
        s_sq[wc][row] = q2;
      }
    }
  }
  __syncthreads();                             // 38
  #pragma unroll
  for (int m = 0; m < 4; ++m) {
    #pragma unroll
    for (int r = 0; r < 4; ++r) {
      int row = wr * 64 + m * 16 + lh * 4 + r;
      float S = 0.f, Q = 0.f;
      #pragma unroll
      for (int w = 0; w < 4; ++w) { S += s_sum[w][row]; Q += s_sq[w][row]; }
      float mean = S * (1.f / 384.f);
      float var = Q * (1.f / 384.f) - mean * mean;
      float rstd = rsqrtf(var + EPS);
      float dotp = 0.f;
      #pragma unroll
      for (int n = 0; n < 6; ++n) {
        float v = acc[m][n][r] + cbv[n];
        float y = fmaxf((v - mean) * rstd * gv[n] + bvv[n], 0.f);
        if constexpr (LAYER == 1) {
          int c = wc * 96 + n * 16 + l15;
          hout[((size_t)(b * (Lz + 2) + l0 + row + 1)) * 384 + c] = f2bf(y);
        } else {
          dotp += y * lwv[n];
        }
      }
      if constexpr (LAYER == 2) {
        #pragma unroll
        for (int off = 1; off < 16; off <<= 1) dotp += __shfl_xor(dotp, off);
        if (l15 == 0) s_dot[wc][row] = dotp;
      }
    }
  }
  if constexpr (LAYER == 2) {
    __syncthreads();                           // 39
    if (tid < 128) {
      float dsum = lbias[0];
      #pragma unroll
      for (int w = 0; w < 4; ++w) dsum += s_dot[w][tid];
      dur[(size_t)b * Lz + l0 + tid] = fmaxf(dsum, 0.f);
    }
  }
}

extern "C" void kernel_launch(void* const* d_in, const int* in_sizes, int n_in,
                              void* d_out, int out_size, void* d_ws, size_t ws_size,
                              hipStream_t stream) {
  (void)in_sizes; (void)n_in; (void)out_size; (void)ws_size;
  const float* x   = (const float*)d_in[0];
  const int* tgt   = (const int*)d_in[1];
  const float* w1  = (const float*)d_in[3];
  const float* c1b = (const float*)d_in[4];
  const float* g1  = (const float*)d_in[5];
  const float* b1  = (const float*)d_in[6];
  const float* w2  = (const float*)d_in[7];
  const float* c2b = (const float*)d_in[8];
  const float* g2  = (const float*)d_in[9];
  const float* b2  = (const float*)d_in[10];
  const float* lw  = (const float*)d_in[11];
  const float* lb  = (const float*)d_in[12];

  float* out0 = (float*)d_out;
  float* dur  = out0 + (size_t)Bz * Mz * Dz;

  const size_t xbf_n = (size_t)Bz * (Lz + 2) * Dz;  // 12,607,488 bf16
  const size_t wt_n  = (size_t)KWz * Fz * Dz;       // 442,368 bf16
  u16* xbf = (u16*)d_ws;
  u16* h1  = xbf + xbf_n;
  u16* w1t = h1 + xbf_n;
  u16* w2t = w1t + wt_n;
  int* idxb = (int*)(w2t + wt_n);  // byte offset divisible by 4

  constexpr int CONV_BLKS = (Bz * Lz * Dz / 8) / 1024;   // 1536
  constexpr int PREP_BLKS = (2 * KWz * Fz * Dz + 2 * Bz * 2 * Dz + 1023) / 1024;
  k_pre<<<CONV_BLKS + PREP_BLKS + Bz, 1024, 0, stream>>>(x, xbf, w1, w2, w1t, w2t,
                                                         h1, tgt, idxb);
  k_conv<1><<<256, 768, 0, stream>>>(xbf, w1t, c1b, g1, b1, h1, nullptr, nullptr,
                                     nullptr, x, idxb, out0);
  k_conv<2><<<256, 768, 0, stream>>>(h1, w2t, c2b, g2, b2, nullptr, lw, lb, dur,
                                     x, idxb, out0);
}

// Round 6
// 180.530 us; speedup vs baseline: 1.0008x; 1.0008x over previous
//
#include <hip/hip_runtime.h>

#define DEV __device__ __forceinline__

typedef unsigned short u16;
typedef __attribute__((ext_vector_type(8))) short bf16x8;   // 8 bf16 (4 VGPRs)
typedef __attribute__((ext_vector_type(8))) unsigned short u16x8;
typedef __attribute__((ext_vector_type(4))) float f32x4;

constexpr int Bz = 32, Lz = 1024, Dz = 384, Fz = 384, KWz = 3, Mz = 4096;
constexpr float EPS = 1e-5f;

DEV u16 f2bf(float f) {  // RNE f32 -> bf16
  unsigned u = __float_as_uint(f);
  u += 0x7fffu + ((u >> 16) & 1u);
  return (u16)(u >> 16);
}

typedef __attribute__((address_space(1))) const unsigned char ga_t;
typedef __attribute__((address_space(3))) unsigned char la_t;
DEV void gload16(const void* g, void* l) {
  // async global->LDS, 16B per lane; LDS dest is wave-uniform base + lane*16
  __builtin_amdgcn_global_load_lds((ga_t*)g, (la_t*)l, 16, 0, 0);
}

// -- fused: convert x -> padded bf16, weight prep, halo zero, cumsum+search --
__global__ __launch_bounds__(1024) void k_pre(
    const float* __restrict__ x, u16* __restrict__ xbf,
    const float* __restrict__ w1, const float* __restrict__ w2,
    u16* __restrict__ w1t, u16* __restrict__ w2t, u16* __restrict__ h1,
    const int* __restrict__ tgt, int* __restrict__ idxb) {
  __shared__ int sc[Lz];
  constexpr int CONV_BLKS = (Bz * Lz * Dz / 8) / 1024;   // 1536
  constexpr int WT = KWz * Fz * Dz;                      // 442368
  constexpr int PREP_ELEMS = 2 * WT + 2 * Bz * 2 * Dz;   // 933888
  constexpr int PREP_BLKS = (PREP_ELEMS + 1023) / 1024;  // 912
  const int tid = threadIdx.x;

  if (blockIdx.x < CONV_BLKS) {  // ---- x f32 -> bf16, padded rows ----
    int gid = blockIdx.x * 1024 + tid;
    size_t e = (size_t)gid * 8;
    float4 v0 = *reinterpret_cast<const float4*>(x + e);
    float4 v1 = *reinterpret_cast<const float4*>(x + e + 4);
    int d = (int)(e % Dz);               // 8 | 384 -> never crosses a row
    int l = (int)((e / Dz) % Lz);
    int b = (int)(e / ((size_t)Dz * Lz));
    u16x8 u;
    u[0] = f2bf(v0.x); u[1] = f2bf(v0.y); u[2] = f2bf(v0.z); u[3] = f2bf(v0.w);
    u[4] = f2bf(v1.x); u[5] = f2bf(v1.y); u[6] = f2bf(v1.z); u[7] = f2bf(v1.w);
    *reinterpret_cast<u16x8*>(xbf + ((size_t)(b * (Lz + 2) + l + 1)) * Dz + d) = u;
    return;
  }
  if (blockIdx.x < CONV_BLKS + PREP_BLKS) {  // ---- weights + halos ----
    int gid = (blockIdx.x - CONV_BLKS) * 1024 + tid;
    if (gid < WT) {
      int k = gid / (Fz * Dz), rem = gid % (Fz * Dz);
      int f = rem / Dz, d = rem % Dz;
      w1t[gid] = f2bf(w1[(f * Dz + d) * KWz + k]);
    } else if (gid < 2 * WT) {
      int g2 = gid - WT;
      int k = g2 / (Fz * Fz), rem = g2 % (Fz * Fz);
      int co = rem / Fz, ci = rem % Fz;
      w2t[g2] = f2bf(w2[(co * Fz + ci) * KWz + k]);
    } else if (gid < PREP_ELEMS) {
      int p = gid - 2 * WT;
      u16* buf = (p < Bz * 2 * Dz) ? xbf : h1;
      int q = p % (Bz * 2 * Dz);
      int b = q / (2 * Dz), r = (q / Dz) & 1, d = q % Dz;
      size_t row = (size_t)b * (Lz + 2) + (r ? (Lz + 1) : 0);
      buf[row * Dz + d] = 0;
    }
    return;
  }
  // ---- cumsum + searchsorted(right) ----
  int b = blockIdx.x - CONV_BLKS - PREP_BLKS;
  sc[tid] = tgt[b * Lz + tid];
  __syncthreads();
  for (int off = 1; off < Lz; off <<= 1) {
    int add = (tid >= off) ? sc[tid - off] : 0;
    __syncthreads();
    sc[tid] += add;
    __syncthreads();
  }
  int total = sc[Lz - 1];
  for (int t = tid; t < Mz; t += 1024) {
    int lo = 0, hi = Lz;
    while (lo < hi) {
      int mid = (lo + hi) >> 1;
      if (sc[mid] > t) hi = mid; else lo = mid + 1;
    }
    int iv = (t < total) ? (lo > Lz - 1 ? Lz - 1 : lo) : -1;
    idxb[b * Mz + t] = iv;
  }
}

// --------- fused conv1d(K=3,'same') + LayerNorm + ReLU (+ final dot) --------
// Waves 0-7: R4-winning GEMM schedule (triple-buffer, counted vmcnt(4)).
// Waves 8-11: gather, fully latency-decoupled: idx prefetched pre-loop,
//   depth-3 row pipeline (load pair kt+2, store pair kt), static slot rotation.
// Barrier count per path: 36 (loop) + 2 (epilogue) + (LAYER==2 ? 1 : 0).
template <int LAYER>
__global__ __launch_bounds__(768, 3) void k_conv(
    const u16* __restrict__ in,    // [Bz][Lz+2][384] bf16 (halo-padded)
    const u16* __restrict__ wt,    // [3][384 out][384 in] bf16
    const float* __restrict__ cbias,
    const float* __restrict__ lng, const float* __restrict__ lnb,
    u16* __restrict__ hout,        // LAYER==1: padded output buffer
    const float* __restrict__ lw, const float* __restrict__ lbias,
    float* __restrict__ dur,       // LAYER==2: [B*L]
    const float* __restrict__ xf,  // gather: source rows (f32)
    const int* __restrict__ idxb,  // gather: per-frame phoneme idx (-1 = pad)
    float* __restrict__ out0)      // gather: [B*M*D]
{
  __shared__ __align__(16) u16 Ash[3][128 * 32];   // 3 x 8KB
  __shared__ __align__(16) u16 Bsh[3][384 * 32];   // 3 x 24KB
  __shared__ float s_sum[4][128], s_sq[4][128], s_dot[4][128];

  const int tid = threadIdx.x;
  const int lane = tid & 63;
  const int wave_u = __builtin_amdgcn_readfirstlane(tid >> 6);  // SGPR wave id
  const int l15 = lane & 15, lh = lane >> 4;
  const int b = blockIdx.x >> 3, l0 = (blockIdx.x & 7) << 7;

  if (wave_u >= 8) {  // ================= gather waves =================
    const int gw = wave_u - 8;
    const int rbase = (LAYER == 1 ? 0 : (Bz * Mz) / 2) + blockIdx.x * 256 + gw * 64;
    const int myidx = idxb[rbase + lane];   // idx prefetch: 1 coalesced load

    float4 A0[3], B0[3], A1[3], B1[3];      // 3 slots, statically indexed only

    auto ldpair = [&](int p, float4& a0, float4& b0q, float4& a1, float4& b1q) {
      int r0 = rbase + 2 * p;
      int iv0 = __shfl(myidx, 2 * p), iv1 = __shfl(myidx, 2 * p + 1);
      if (iv0 < 0) { a0 = make_float4(0.f, 0.f, 0.f, 0.f); b0q = a0; }
      else {
        const float4* s =
            reinterpret_cast<const float4*>(xf + ((size_t)(r0 >> 12) * Lz + iv0) * Dz);
        a0 = s[lane]; b0q = (lane < 32) ? s[64 + lane] : a0;
      }
      if (iv1 < 0) { a1 = make_float4(0.f, 0.f, 0.f, 0.f); b1q = a1; }
      else {
        const float4* s =
            reinterpret_cast<const float4*>(xf + ((size_t)((r0 + 1) >> 12) * Lz + iv1) * Dz);
        a1 = s[lane]; b1q = (lane < 32) ? s[64 + lane] : a1;
      }
    };
    auto stpair = [&](int p, float4 a0, float4 b0q, float4 a1, float4 b1q) {
      int r0 = rbase + 2 * p;
      float4* d0 = reinterpret_cast<float4*>(out0 + (size_t)r0 * Dz);
      d0[lane] = a0; if (lane < 32) d0[64 + lane] = b0q;
      float4* d1 = reinterpret_cast<float4*>(out0 + (size_t)(r0 + 1) * Dz);
      d1[lane] = a1; if (lane < 32) d1[64 + lane] = b1q;
    };

    ldpair(0, A0[0], B0[0], A1[0], B1[0]);
    ldpair(1, A0[1], B0[1], A1[1], B1[1]);
    // step(kt): load pair kt+2 into slot (kt+2)%3; store pair kt from slot kt%3
    for (int k3 = 0; k3 < 12; ++k3) {
      int kt = 3 * k3;
      if (kt < 30) ldpair(kt + 2, A0[2], B0[2], A1[2], B1[2]);
      if (kt < 32) stpair(kt, A0[0], B0[0], A1[0], B1[0]);
      __builtin_amdgcn_s_barrier();            // kt = 3k3
      ++kt;
      if (kt < 30) ldpair(kt + 2, A0[0], B0[0], A1[0], B1[0]);
      if (kt < 32) stpair(kt, A0[1], B0[1], A1[1], B1[1]);
      __builtin_amdgcn_s_barrier();            // kt = 3k3+1
      ++kt;
      if (kt < 30) ldpair(kt + 2, A0[1], B0[1], A1[1], B1[1]);
      if (kt < 32) stpair(kt, A0[2], B0[2], A1[2], B1[2]);
      __builtin_amdgcn_s_barrier();            // kt = 3k3+2
    }
    __builtin_amdgcn_s_barrier();                // 37
    __builtin_amdgcn_s_barrier();                // 38
    if constexpr (LAYER == 2) __builtin_amdgcn_s_barrier();  // 39
    return;
  }

  // ================= conv waves (identical to R4 schedule) =================
  const int wr = wave_u >> 2, wc = wave_u & 3;  // 2 x 4 wave grid (SGPR)

  const u16* in_row = in + ((size_t)(b * (Lz + 2) + l0)) * 384;
  int gof[4], ldo[4];
  bool isa[4];
  #pragma unroll
  for (int i = 0; i < 4; ++i) {
    int c = wave_u + 8 * i;
    bool a = (c < 8);
    int cb = a ? c : c - 8;                  // SGPR
    int slot = cb * 64 + lane, r = slot >> 2, q = slot & 3;
    int ks = q ^ ((r >> 1) & 3);             // XOR slot swizzle (involution)
    gof[i] = r * 384 + ks * 8;               // VGPR (lane-dependent)
    ldo[i] = cb * 512;                       // SGPR
    isa[i] = a;
  }

  auto STAGE = [&](int kt, int buf) {
    int tap = kt / 12;
    int d0 = (kt - tap * 12) * 32;
    const u16* sa = in_row + tap * 384 + d0;
    const u16* sb = wt + tap * (384 * 384) + d0;
    #pragma unroll
    for (int i = 0; i < 4; ++i) {
      if (isa[i]) gload16(sa + gof[i], &Ash[buf][ldo[i]]);
      else        gload16(sb + gof[i], &Bsh[buf][ldo[i]]);
    }
  };

  int aoff[4], boff[6];
  #pragma unroll
  for (int m = 0; m < 4; ++m) {
    int r = wr * 64 + m * 16 + l15;
    aoff[m] = r * 32 + (lh ^ ((r >> 1) & 3)) * 8;
  }
  #pragma unroll
  for (int n = 0; n < 6; ++n) {
    int c = wc * 96 + n * 16 + l15;
    boff[n] = c * 32 + (lh ^ ((c >> 1) & 3)) * 8;
  }

  f32x4 acc[4][6] = {};

  STAGE(0, 0);
  STAGE(1, 1);
  int cur = 0;
  for (int kt = 0; kt < 36; ++kt) {
    if (kt < 35) asm volatile("s_waitcnt vmcnt(4)" ::: "memory");
    else         asm volatile("s_waitcnt vmcnt(0)" ::: "memory");
    __builtin_amdgcn_s_barrier();              // 1..36
    __builtin_amdgcn_sched_barrier(0);
    bf16x8 av[4], bv[6];
    #pragma unroll
    for (int m = 0; m < 4; ++m)
      av[m] = *reinterpret_cast<const bf16x8*>(&Ash[cur][aoff[m]]);
    #pragma unroll
    for (int n = 0; n < 6; ++n)
      bv[n] = *reinterpret_cast<const bf16x8*>(&Bsh[cur][boff[n]]);
    if (kt < 34) {
      int nb = cur + 2; if (nb >= 3) nb -= 3;
      STAGE(kt + 2, nb);  // buf last read at step kt-1; barrier-protected
    }
    #pragma unroll
    for (int m = 0; m < 4; ++m)
      #pragma unroll
      for (int n = 0; n < 6; ++n)
        acc[m][n] =
            __builtin_amdgcn_mfma_f32_16x16x32_bf16(av[m], bv[n], acc[m][n], 0, 0, 0);
    cur = (cur == 2) ? 0 : cur + 1;
  }

  // ---- epilogue: bias + LayerNorm(F) + ReLU, then store bf16 or dot(lw) ----
  __syncthreads();                             // 37
  float gv[6], bvv[6], cbv[6], lwv[6];
  #pragma unroll
  for (int n = 0; n < 6; ++n) {
    int c = wc * 96 + n * 16 + l15;
    gv[n] = lng[c]; bvv[n] = lnb[c]; cbv[n] = cbias[c];
    lwv[n] = (LAYER == 2) ? lw[c] : 0.f;
  }
  #pragma unroll
  for (int m = 0; m < 4; ++m) {
    #pragma unroll
    for (int r = 0; r < 4; ++r) {
      float s = 0.f, q2 = 0.f;
      #pragma unroll
      for (int n = 0; n < 6; ++n) {
        float v = acc[m][n][r] + cbv[n];
        s += v; q2 += v * v;
      }
      #pragma unroll
      for (int off = 1; off < 16; off <<= 1) {
        s += __shfl_xor(s, off);
        q2 += __shfl_xor(q2, off);
      }
      if (l15 == 0) {
        int row = wr * 64 + m * 16 + lh * 4 + r;
        s_sum[wc][row] = s;
        s_sq[wc][row] = q2;
      }
    }
  }
  __syncthreads();                             // 38
  #pragma unroll
  for (int m = 0; m < 4; ++m) {
    #pragma unroll
    for (int r = 0; r < 4; ++r) {
      int row = wr * 64 + m * 16 + lh * 4 + r;
      float S = 0.f, Q = 0.f;
      #pragma unroll
      for (int w = 0; w < 4; ++w) { S += s_sum[w][row]; Q += s_sq[w][row]; }
      float mean = S * (1.f / 384.f);
      float var = Q * (1.f / 384.f) - mean * mean;
      float rstd = rsqrtf(var + EPS);
      float dotp = 0.f;
      #pragma unroll
      for (int n = 0; n < 6; ++n) {
        float v = acc[m][n][r] + cbv[n];
        float y = fmaxf((v - mean) * rstd * gv[n] + bvv[n], 0.f);
        if constexpr (LAYER == 1) {
          int c = wc * 96 + n * 16 + l15;
          hout[((size_t)(b * (Lz + 2) + l0 + row + 1)) * 384 + c] = f2bf(y);
        } else {
          dotp += y * lwv[n];
        }
      }
      if constexpr (LAYER == 2) {
        #pragma unroll
        for (int off = 1; off < 16; off <<= 1) dotp += __shfl_xor(dotp, off);
        if (l15 == 0) s_dot[wc][row] = dotp;
      }
    }
  }
  if constexpr (LAYER == 2) {
    __syncthreads();                           // 39
    if (tid < 128) {
      float dsum = lbias[0];
      #pragma unroll
      for (int w = 0; w < 4; ++w) dsum += s_dot[w][tid];
      dur[(size_t)b * Lz + l0 + tid] = fmaxf(dsum, 0.f);
    }
  }
}

extern "C" void kernel_launch(void* const* d_in, const int* in_sizes, int n_in,
                              void* d_out, int out_size, void* d_ws, size_t ws_size,
                              hipStream_t stream) {
  (void)in_sizes; (void)n_in; (void)out_size; (void)ws_size;
  const float* x   = (const float*)d_in[0];
  const int* tgt   = (const int*)d_in[1];
  const float* w1  = (const float*)d_in[3];
  const float* c1b = (const float*)d_in[4];
  const float* g1  = (const float*)d_in[5];
  const float* b1  = (const float*)d_in[6];
  const float* w2  = (const float*)d_in[7];
  const float* c2b = (const float*)d_in[8];
  const float* g2  = (const float*)d_in[9];
  const float* b2  = (const float*)d_in[10];
  const float* lw  = (const float*)d_in[11];
  const float* lb  = (const float*)d_in[12];

  float* out0 = (float*)d_out;
  float* dur  = out0 + (size_t)Bz * Mz * Dz;

  const size_t xbf_n = (size_t)Bz * (Lz + 2) * Dz;  // 12,607,488 bf16
  const size_t wt_n  = (size_t)KWz * Fz * Dz;       // 442,368 bf16
  u16* xbf = (u16*)d_ws;
  u16* h1  = xbf + xbf_n;
  u16* w1t = h1 + xbf_n;
  u16* w2t = w1t + wt_n;
  int* idxb = (int*)(w2t + wt_n);  // byte offset divisible by 4

  constexpr int CONV_BLKS = (Bz * Lz * Dz / 8) / 1024;   // 1536
  constexpr int PREP_BLKS = (2 * KWz * Fz * Dz + 2 * Bz * 2 * Dz + 1023) / 1024;
  k_pre<<<CONV_BLKS + PREP_BLKS + Bz, 1024, 0, stream>>>(x, xbf, w1, w2, w1t, w2t,
                                                         h1, tgt, idxb);
  k_conv<1><<<256, 768, 0, stream>>>(xbf, w1t, c1b, g1, b1, h1, nullptr, nullptr,
                                     nullptr, x, idxb, out0);
  k_conv<2><<<256, 768, 0, stream>>>(h1, w2t, c2b, g2, b2, nullptr, lw, lb, dur,
                                     x, idxb, out0);
}